// Round 3
// baseline (152.729 us; speedup 1.0000x reference)
//
#include <hip/hip_runtime.h>
#include <hip/hip_bf16.h>

// Problem constants (B=1 folded out)
#define SDIM 2
#define NPT  6144      // N = H*W
#define CDIM 128
#define H0   64
#define W0   96

// bf16 pyramid level offsets in uint (bf16-pair) units
// L0: 2*64*96*64 = 786432 ; L1: 196608 ; L2: 49152 ; L3: 12288
__constant__ int c_lvl_off[4] = {0, 786432, 983040, 1032192};

__device__ __forceinline__ float bf_lo(unsigned u) { return __uint_as_float(u << 16); }
__device__ __forceinline__ float bf_hi(unsigned u) { return __uint_as_float(u & 0xffff0000u); }

__device__ __forceinline__ unsigned pack_bf16(float a, float b) {
    unsigned ua = __float_as_uint(a);
    ua = (ua + 0x7fffu + ((ua >> 16) & 1u)) >> 16;
    unsigned ub = __float_as_uint(b);
    ub = (ub + 0x7fffu + ((ub >> 16) & 1u)) >> 16;
    return ua | (ub << 16);
}

// features [S][C][H0*W0] f32  ->  pyr L0 [S][H0*W0][C] bf16 (as uint pairs)
__global__ __launch_bounds__(256) void transpose_kernel(const float* __restrict__ feat,
                                                        unsigned* __restrict__ out) {
    __shared__ float lds[64 * 129];
    const int bid = blockIdx.x;
    const int s = bid / 96;
    const int p0 = (bid % 96) * 64;
    const int tid = threadIdx.x;
    const int sub = tid >> 6;   // 0..3
    const int lane = tid & 63;
#pragma unroll
    for (int k = 0; k < 32; ++k) {
        int c = sub + k * 4;
        lds[lane * 129 + c] = feat[(s * CDIM + c) * (H0 * W0) + p0 + lane];
    }
    __syncthreads();
#pragma unroll
    for (int k = 0; k < 16; ++k) {
        int pl = sub + k * 4;                 // 0..63
        float lo = lds[pl * 129 + lane * 2];
        float hi = lds[pl * 129 + lane * 2 + 1];
        out[(size_t)(s * (H0 * W0) + p0 + pl) * 64 + lane] = pack_bf16(lo, hi);
    }
}

// 2x2 average pool, bf16 [S][2H2][2W2][C] -> [S][H2][W2][C]
__global__ __launch_bounds__(256) void pool_kernel(const unsigned* __restrict__ in,
                                                   unsigned* __restrict__ out,
                                                   int H2, int W2) {
    int idx = blockIdx.x * 256 + threadIdx.x;
    int total = SDIM * H2 * W2 * 64;
    if (idx >= total) return;
    int cp = idx & 63;
    int pix = idx >> 6;
    int x2 = pix % W2;
    int t = pix / W2;
    int y2 = t % H2;
    int s = t / H2;
    int W1 = W2 * 2;
    int base = ((s * (H2 * 2) + y2 * 2) * W1 + x2 * 2) * 64 + cp;
    int sy = W1 * 64;
    unsigned u00 = in[base], u01 = in[base + 64];
    unsigned u10 = in[base + sy], u11 = in[base + sy + 64];
    float lo = (bf_lo(u00) + bf_lo(u01) + bf_lo(u10) + bf_lo(u11)) * 0.25f;
    float hi = (bf_hi(u00) + bf_hi(u01) + bf_hi(u10) + bf_hi(u11)) * 0.25f;
    out[idx] = pack_bf16(lo, hi);
}

// One block per (s,n). Wave w = pyramid level w. 4-lane groups own lattice points.
__global__ __launch_bounds__(256) void corr_kernel(const float* __restrict__ targets,
                                                   const float* __restrict__ coords,
                                                   const unsigned* __restrict__ pyr,
                                                   float* __restrict__ out) {
    __shared__ __align__(16) float tgt[CDIM];
    __shared__ float Ds[4][112];

    const int sn = blockIdx.x;           // 0 .. S*N-1
    const int tid = threadIdx.x;

    if (tid < CDIM) tgt[tid] = targets[(size_t)sn * CDIM + tid];
    const float cx = coords[sn * 2 + 0];
    const float cy = coords[sn * 2 + 1];
    __syncthreads();

    const int lvl = tid >> 6;
    const int lane = tid & 63;
    const int g = lane >> 2;
    const int k = lane & 3;

    const int Wi = W0 >> lvl;
    const int Hi = H0 >> lvl;
    const int s = sn / NPT;
    const unsigned* base = pyr + c_lvl_off[lvl] + s * Hi * Wi * 64;

    const float scale = 1.0f / (float)(1 << lvl);
    const float cxl = cx * scale, cyl = cy * scale;
    const float x0f = floorf(cxl), y0f = floorf(cyl);
    const float wx1 = cxl - x0f, wx0 = 1.0f - wx1;
    const float wy1 = cyl - y0f, wy0 = 1.0f - wy1;
    const int ix0 = (int)x0f - 4;
    const int iy0 = (int)y0f - 4;

    // preload this lane's 32-element target slice
    float treg[32];
#pragma unroll
    for (int q = 0; q < 8; ++q) {
        float4 v = *(const float4*)&tgt[k * 32 + q * 4];
        treg[q * 4 + 0] = v.x; treg[q * 4 + 1] = v.y;
        treg[q * 4 + 2] = v.z; treg[q * 4 + 3] = v.w;
    }

    for (int it = 0; it < 7; ++it) {
        int p = it * 16 + g;                 // lattice point id, row-major [y][x]
        int row = (p * 205) >> 11;           // p / 10 (valid for p < 128)
        int col = p - row * 10;
        int y = iy0 + row;
        int x = ix0 + col;
        bool valid = ((unsigned)x < (unsigned)Wi) && ((unsigned)y < (unsigned)Hi);
        int xc = min(max(x, 0), Wi - 1);
        int yc = min(max(y, 0), Hi - 1);
        const uint4* ptr = (const uint4*)(base + (yc * Wi + xc) * 64 + k * 16);
        float acc = 0.0f;
#pragma unroll
        for (int q = 0; q < 4; ++q) {
            uint4 v = ptr[q];
            acc = fmaf(bf_lo(v.x), treg[q * 8 + 0], acc);
            acc = fmaf(bf_hi(v.x), treg[q * 8 + 1], acc);
            acc = fmaf(bf_lo(v.y), treg[q * 8 + 2], acc);
            acc = fmaf(bf_hi(v.y), treg[q * 8 + 3], acc);
            acc = fmaf(bf_lo(v.z), treg[q * 8 + 4], acc);
            acc = fmaf(bf_hi(v.z), treg[q * 8 + 5], acc);
            acc = fmaf(bf_lo(v.w), treg[q * 8 + 6], acc);
            acc = fmaf(bf_hi(v.w), treg[q * 8 + 7], acc);
        }
        acc += __shfl_xor(acc, 1);
        acc += __shfl_xor(acc, 2);
        if (k == 0 && p < 100) Ds[lvl][p] = valid ? acc : 0.0f;
    }

    __syncthreads();

    const float isc = 0.08838834764831843f;  // 1/sqrt(128)
    const size_t obase = (size_t)sn * 324 + lvl * 81;
#pragma unroll
    for (int r = 0; r < 2; ++r) {
        int o = r * 64 + lane;
        if (o < 81) {
            int j = (o * 57) >> 9;           // o / 9  -> x-offset index (outer)
            int i = o - j * 9;               //          y-offset index (inner)
            float d00 = Ds[lvl][i * 10 + j];
            float d01 = Ds[lvl][i * 10 + j + 1];
            float d10 = Ds[lvl][(i + 1) * 10 + j];
            float d11 = Ds[lvl][(i + 1) * 10 + j + 1];
            float v = wy0 * (wx0 * d00 + wx1 * d01) + wy1 * (wx0 * d10 + wx1 * d11);
            out[obase + o] = v * isc;
        }
    }
}

extern "C" void kernel_launch(void* const* d_in, const int* in_sizes, int n_in,
                              void* d_out, int out_size, void* d_ws, size_t ws_size,
                              hipStream_t stream) {
    const float* features = (const float*)d_in[0];   // [1,2,128,64,96]
    const float* targets  = (const float*)d_in[1];   // [1,2,6144,128]
    const float* coords   = (const float*)d_in[2];   // [1,2,6144,2]
    float* out = (float*)d_out;                      // [1,2,6144,324]

    unsigned* pyr = (unsigned*)d_ws;                 // bf16 pyramid, 4,177,920 B

    // L0 transpose: [S][C][HW] f32 -> [S][HW][C] bf16
    transpose_kernel<<<SDIM * (H0 * W0 / 64), 256, 0, stream>>>(features, pyr);

    // pyramid pools
    pool_kernel<<<(SDIM * 32 * 48 * 64 + 255) / 256, 256, 0, stream>>>(
        pyr + 0,       pyr + 786432, 32, 48);
    pool_kernel<<<(SDIM * 16 * 24 * 64 + 255) / 256, 256, 0, stream>>>(
        pyr + 786432,  pyr + 983040, 16, 24);
    pool_kernel<<<(SDIM * 8 * 12 * 64 + 255) / 256, 256, 0, stream>>>(
        pyr + 983040,  pyr + 1032192, 8, 12);

    // fused correlate + window sample
    corr_kernel<<<SDIM * NPT, 256, 0, stream>>>(targets, coords, pyr, out);
}